// Round 2
// baseline (228.113 us; speedup 1.0000x reference)
//
#include <hip/hip_runtime.h>
#include <math.h>

// ---------------------------------------------------------------------------
// Epipolar GN solver via 4th-order moment sufficient statistics.
//   r   = p2^T E p1,  a_k = p2^T M_k p1  with p=(u,v,1)
//   All per-iteration sums (J^T J, J^T res, sum res) are contractions of
//   Mom[i2,i1] = sum_n u2^a2 v2^b2 u1^a1 v1^b1  (deg<=4 each frame, 15x15).
// Pipeline: zero ws -> k_mom (O(N), fp64 moments) -> k_iter (1 wave, 100 GN
// steps in fp64, O(1) each) -> k_loss (O(N) |p2^T F p1|) -> k_fin.
// Round-2 fixes: (a) Gauss-Jordan used tid<72 with a 64-thread block -> row 5
// of aug never written -> bad_inv at it=0 -> t frozen (the round-1 failure).
// (b) whole iteration promoted to fp64 to track the exact trajectory (stop
// test `curloss > min_loss` at the plateau is the chaotic part).
// ---------------------------------------------------------------------------

#define LAPL 0.01
#define LRR  0.1
static constexpr int TS  = 128;   // points per tile in k_mom
static constexpr int TSP = 129;   // padded LDS row stride (conflict-free)

__host__ __device__ constexpr int IDXe(int a, int b) { return (a + b) * (a + b + 1) / 2 + b; }

// monomial index (deg<=2, 0..5) -> exponents (a,b)
__device__ static const int EA6[6] = {0, 1, 0, 2, 1, 0};
__device__ static const int EB6[6] = {0, 0, 1, 0, 1, 2};
// the 21 (k<=l) pairs for Q_kl
__device__ static const signed char QKt[21] = {0,0,0,0,0,0, 1,1,1,1,1, 2,2,2,2, 3,3,3, 4,4, 5};
__device__ static const signed char QLt[21] = {0,1,2,3,4,5, 1,2,3,4,5, 2,3,4,5, 3,4,5, 4,5, 5};

__device__ __forceinline__ void kinv3d(const float* K, double ki[9]) {
  double a = K[0], b = K[1], c = K[2], d = K[3], e = K[4], f = K[5], g = K[6], h = K[7], i = K[8];
  double A = (e * i - f * h), B = -(d * i - f * g), C = (d * h - e * g);
  double det = a * A + b * B + c * C;
  double r = 1.0 / det;
  ki[0] = A * r;             ki[1] = -(b * i - c * h) * r;  ki[2] =  (b * f - c * e) * r;
  ki[3] = B * r;             ki[4] =  (a * i - c * g) * r;  ki[5] = -(a * f - c * d) * r;
  ki[6] = C * r;             ki[7] = -(a * h - b * g) * r;  ki[8] =  (a * e - b * d) * r;
}

__device__ __forceinline__ void mm3d(const double* A, const double* B, double* C) {
#pragma unroll
  for (int i = 0; i < 3; ++i)
#pragma unroll
    for (int j = 0; j < 3; ++j)
      C[i * 3 + j] = A[i * 3 + 0] * B[0 * 3 + j] + A[i * 3 + 1] * B[1 * 3 + j] + A[i * 3 + 2] * B[2 * 3 + j];
}

// ws layout (doubles): [0 .. 8*225)  8 copies of Mom partials
//                      [1800 .. 1808) 8 loss partials
__global__ __launch_bounds__(256) void k_zero(double* ws) {
  for (int i = threadIdx.x; i < 1808; i += 256) ws[i] = 0.0;
}

__global__ __launch_bounds__(256) void k_mom(const float* __restrict__ P1, const float* __restrict__ P2f,
                                             const float* __restrict__ K, double* __restrict__ mom, int N) {
  __shared__ double md[2][15][TSP];   // [frame][monomial][point]
  double ki[9];
  kinv3d(K, ki);
  const int t = threadIdx.x;
  const int j2 = t / 15, j1 = t % 15;
  double acc = 0.0;
  for (int base = blockIdx.x * TS; base < N; base += gridDim.x * TS) {
    {  // phase 1: threads 0..127 -> frame1 monomials, 128..255 -> frame2
      const int f = t >> 7;
      const int p = t & 127;
      const int idx = base + p;
      double m[15];
      if (idx < N) {
        const float* P = f ? P2f : P1;
        double x = (double)P[idx], y = (double)P[N + idx];
        double u = ki[0] * x + ki[1] * y + ki[2];
        double v = ki[3] * x + ki[4] * y + ki[5];
        double pu[5], pv[5];
        pu[0] = 1.0; pv[0] = 1.0;
        pu[1] = u;  pv[1] = v;
        pu[2] = pu[1] * pu[1]; pv[2] = pv[1] * pv[1];
        pu[3] = pu[2] * pu[1]; pv[3] = pv[2] * pv[1];
        pu[4] = pu[2] * pu[2]; pv[4] = pv[2] * pv[2];
#pragma unroll
        for (int d = 0; d <= 4; ++d)
#pragma unroll
          for (int bb = 0; bb <= d; ++bb)
            m[(d * (d + 1)) / 2 + bb] = pu[d - bb] * pv[bb];
      } else {
#pragma unroll
        for (int q = 0; q < 15; ++q) m[q] = 0.0;
      }
#pragma unroll
      for (int q = 0; q < 15; ++q) md[f][q][p] = m[q];
    }
    __syncthreads();
    if (t < 225) {
#pragma unroll 4
      for (int p = 0; p < TS; ++p) acc += md[1][j2][p] * md[0][j1][p];
    }
    __syncthreads();
  }
  if (t < 225) unsafeAtomicAdd(&mom[(blockIdx.x & 7) * 225 + t], acc);
}

__global__ __launch_bounds__(64) void k_iter(const double* __restrict__ mom, const float* __restrict__ Kg,
                                             float* __restrict__ out, int N) {
  __shared__ struct {
    double Mom[225];
    double G[36 * 37];    // G[row*37+col]: row-padded vs bank conflicts
    double U0[81];
    double uu[36];
    double gg[36];
    double zd[7][9];      // 0: E, 1..6: M_k
    double Y[7][9];       // U2 * zd[l]
    double w0[9];         // U0 * e
    double Qs[6][6];
    double Cs[6];
    double Ps[6];
    double P2s;
    double Mm[36];
    double vv[6];
    double upd[6];
    double aug[72];       // 6x12 Gauss-Jordan (fp64)
    double sc[6];
    int mul9[81];
    int gcnt[36];
    int gpr[36 * 8];
  } S;
  const int tid = threadIdx.x;
  const double dN = (double)N;
  const double inv2 = 1.0 / (dN * dN);

  // ---------------- prologue: moments + constant tables ----------------
  for (int i = tid; i < 225; i += 64) {
    double a = 0.0;
#pragma unroll
    for (int c = 0; c < 8; ++c) a += mom[c * 225 + i];
    S.Mom[i] = a;
  }
  for (int i = tid; i < 81; i += 64) {
    int A = i / 9, B = i % 9, ia = A / 3, ja = A % 3, ib = B / 3, jb = B % 3;
    int a2 = (ia == 0) + (ib == 0), b2 = (ia == 1) + (ib == 1);
    int a1 = (ja == 0) + (jb == 0), b1 = (ja == 1) + (jb == 1);
    S.mul9[i] = IDXe(a2, b2) * 6 + IDXe(a1, b1);
  }
  __syncthreads();
  for (int i = tid; i < 1296; i += 64) {
    int ga = i / 36, de = i % 36;
    int g2 = ga / 6, g1 = ga % 6, d2 = de / 6, d1 = de % 6;
    int a2 = EA6[g2] + EA6[d2], b2 = EB6[g2] + EB6[d2];
    int a1 = EA6[g1] + EA6[d1], b1 = EB6[g1] + EB6[d1];
    S.G[ga * 37 + de] = S.Mom[IDXe(a2, b2) * 15 + IDXe(a1, b1)];
  }
  for (int i = tid; i < 81; i += 64) {
    int ga = S.mul9[i];
    S.U0[i] = S.Mom[(ga / 6) * 15 + (ga % 6)];
  }
  if (tid == 0) {
    for (int d = 0; d < 36; ++d) S.gcnt[d] = 0;
    for (int AB = 0; AB < 81; ++AB) {
      int d = S.mul9[AB];
      S.gpr[d * 8 + S.gcnt[d]] = AB;
      S.gcnt[d]++;
    }
  }
  __syncthreads();

  // ---------------- GN iterations (all fp64) ----------------
  double a0 = 0.0, a1 = 0.0, a2v = 0.0;
  double t0 = 0.0, t1 = 0.0, t2 = -0.95;
  double min_loss = 1e10;

  for (int it = 0; it < 100; ++it) {
    if (tid < 3) {
      double av = (tid == 0) ? a0 : ((tid == 1) ? a1 : a2v);
      double sv, cv;
      sincos(av, &sv, &cv);
      S.sc[tid] = cv;
      S.sc[3 + tid] = sv;
    }
    __syncthreads();
    const double cx = S.sc[0], cy = S.sc[1], cz = S.sc[2];
    const double sx = S.sc[3], sy = S.sc[4], sz = S.sc[5];

    // rotation chain (redundant on all lanes)
    double Rz[9] = {cz, -sz, 0, sz, cz, 0, 0, 0, 1};
    double Ry[9] = {cy, 0, sy, 0, 1, 0, -sy, 0, cy};
    double Rx[9] = {1, 0, 0, 0, cx, -sx, 0, sx, cx};
    double Rzd[9] = {-sz, -cz, 0, cz, -sz, 0, 0, 0, 0};
    double Ryd[9] = {-sy, 0, cy, 0, 0, 0, -cy, 0, -sy};
    double Rxd[9] = {0, 0, 0, 0, -sx, -cx, 0, cx, -sx};
    double YX[9], ZY[9], ZYd[9], ZdY[9], R[9], rxd[9], ryd[9], rzd[9];
    mm3d(Ry, Rx, YX);  mm3d(Rz, YX, R);
    mm3d(Rz, Ry, ZY);  mm3d(ZY, Rxd, rxd);
    mm3d(Rz, Ryd, ZYd); mm3d(ZYd, Rx, ryd);
    mm3d(Rzd, Ry, ZdY); mm3d(ZdY, Rx, rzd);
    double Tm[9] = {0, -t2, t1, t2, 0, -t0, -t1, t0, 0};
    double E[9], M0[9], M1[9], M2[9];
    mm3d(Tm, R, E); mm3d(Tm, rxd, M0); mm3d(Tm, ryd, M1); mm3d(Tm, rzd, M2);
    double M3[9] = {0, 0, 0, -R[6], -R[7], -R[8], R[3], R[4], R[5]};
    double M4[9] = {R[6], R[7], R[8], 0, 0, 0, -R[0], -R[1], -R[2]};
    double M5[9] = {-R[3], -R[4], -R[5], R[0], R[1], R[2], 0, 0, 0};

    if (tid == 0) {
#pragma unroll
      for (int q = 0; q < 9; ++q) {
        S.zd[0][q] = E[q];  S.zd[1][q] = M0[q];
        S.zd[2][q] = M1[q]; S.zd[3][q] = M2[q];
        S.zd[4][q] = M3[q]; S.zd[5][q] = M4[q];
        S.zd[6][q] = M5[q];
      }
    }
    __syncthreads();

    // g = coefficients of r^2 over 36 deg-2 monomials
    if (tid < 36) {
      double a = 0.0;
      int n = S.gcnt[tid];
      for (int q = 0; q < n; ++q) {
        int ab = S.gpr[tid * 8 + q];
        a += S.zd[0][ab / 9] * S.zd[0][ab % 9];
      }
      S.gg[tid] = a;
    }
    __syncthreads();

    // u = G * g   (u[gamma] = sum_n r^2 * mono_gamma)
    if (tid < 36) {
      double a = 0.0;
#pragma unroll
      for (int q = 0; q < 36; ++q) a += S.G[tid * 37 + q] * S.gg[q];
      S.uu[tid] = a;
    }
    __syncthreads();

    // Y[l] = U2 * zd[l], U2[A][B] = uu[mul9[A][B]]
    if (tid < 63) {
      int l = tid / 9, A = tid % 9;
      double a = 0.0;
#pragma unroll
      for (int B = 0; B < 9; ++B) a += S.uu[S.mul9[A * 9 + B]] * S.zd[l][B];
      S.Y[l][A] = a;
    }
    __syncthreads();
    if (tid < 9) {
      double a = 0.0;
#pragma unroll
      for (int B = 0; B < 9; ++B) a += S.U0[tid * 9 + B] * S.zd[0][B];
      S.w0[tid] = a;
    }
    __syncthreads();

    // Q_kl = z_k . Y[1+l];  C_k = z_k . Y[0];  P_k = z_k . w0;  P2 = e . w0
    if (tid < 21) {
      int k = QKt[tid], l = QLt[tid];
      double a = 0.0;
#pragma unroll
      for (int A = 0; A < 9; ++A) a += S.zd[1 + k][A] * S.Y[1 + l][A];
      S.Qs[k][l] = a; S.Qs[l][k] = a;
    } else if (tid < 27) {
      int k = tid - 21; double a = 0.0;
#pragma unroll
      for (int A = 0; A < 9; ++A) a += S.zd[1 + k][A] * S.Y[0][A];
      S.Cs[k] = a;
    } else if (tid < 33) {
      int k = tid - 27; double a = 0.0;
#pragma unroll
      for (int A = 0; A < 9; ++A) a += S.zd[1 + k][A] * S.w0[A];
      S.Ps[k] = a;
    } else if (tid == 33) {
      double a = 0.0;
#pragma unroll
      for (int A = 0; A < 9; ++A) a += S.zd[0][A] * S.w0[A];
      S.P2s = a;
    }
    __syncthreads();

    // assemble M (6x6) and v (6)
    double tn = sqrt(t0 * t0 + t1 * t1 + t2 * t2);
    double rbf = tn - 1.0;
    double btc = 2.0 * LAPL * rbf / tn;
    double dcf = (LAPL * rbf * rbf) / dN;             // c
    double curloss = S.P2s / dN + LAPL * rbf * rbf;
#define BVAL(k) ((k) == 3 ? (btc * t0) : (k) == 4 ? (btc * t1) : (k) == 5 ? (btc * t2) : 0.0)
    if (tid < 36) {
      int k = tid / 6, l = tid % 6;
      double bk = BVAL(k), bl = BVAL(l);
      S.Mm[tid] = 4.0 * inv2 * S.Qs[k][l] + 2.0 * inv2 * (bk * S.Ps[l] + bl * S.Ps[k]) + bk * bl / dN;
    } else if (tid < 42) {
      int k = tid - 36;
      double bk = BVAL(k);
      S.vv[k] = 2.0 * inv2 * S.Cs[k] + (2.0 * dcf / dN) * S.Ps[k] + bk * inv2 * S.P2s + bk * dcf;
    }
    __syncthreads();

    // fp64 6x6 Gauss-Jordan -> Minv in right half of aug (72 entries, 64 thr)
    for (int e = tid; e < 72; e += 64) {
      int r = e / 12, c = e % 12;
      S.aug[e] = (c < 6) ? S.Mm[r * 6 + c] : ((c - 6 == r) ? 1.0 : 0.0);
    }
    __syncthreads();
    for (int p = 0; p < 6; ++p) {
      double rp = 1.0 / S.aug[p * 12 + p];
      double prc[2], cur[2], mr[2];
      const int ee0 = tid, ee1 = tid + 64;
      { int e = ee0; int r = e / 12, c = e % 12; prc[0] = S.aug[p * 12 + c]; cur[0] = S.aug[e]; mr[0] = S.aug[r * 12 + p]; }
      if (ee1 < 72) { int e = ee1; int r = e / 12, c = e % 12; prc[1] = S.aug[p * 12 + c]; cur[1] = S.aug[e]; mr[1] = S.aug[r * 12 + p]; }
      __syncthreads();
      { int e = ee0; int r = e / 12; S.aug[e] = (r == p) ? prc[0] * rp : cur[0] - mr[0] * rp * prc[0]; }
      if (ee1 < 72) { int e = ee1; int r = e / 12; S.aug[e] = (r == p) ? prc[1] * rp : cur[1] - mr[1] * rp * prc[1]; }
      __syncthreads();
    }

    // bad_inv check: max|Minv*M - I| > 0.1
    double merr = 0.0;
    if (tid < 36) {
      int i = tid / 6, j = tid % 6;
      double s2 = -((i == j) ? 1.0 : 0.0);
#pragma unroll
      for (int k2 = 0; k2 < 6; ++k2) s2 += S.aug[i * 12 + 6 + k2] * S.Mm[k2 * 6 + j];
      merr = fabs(s2);
    }
#pragma unroll
    for (int off = 32; off; off >>= 1) merr = fmax(merr, __shfl_xor(merr, off));
    bool bad = merr > 0.1;

    if (tid < 6) {
      double a = 0.0;
#pragma unroll
      for (int j = 0; j < 6; ++j) a += S.aug[tid * 12 + 6 + j] * S.vv[j];
      S.upd[tid] = a;
    }
    __syncthreads();

    bool stop_now = bad || (curloss > min_loss);
    if (stop_now) break;                       // latched stop == params frozen forever
    a0 -= LRR * S.upd[0]; a1 -= LRR * S.upd[1]; a2v -= LRR * S.upd[2];
    t0 -= LRR * S.upd[3]; t1 -= LRR * S.upd[4]; t2 -= LRR * S.upd[5];
    min_loss = curloss;
    __syncthreads();
  }

  // ---------------- epilogue: F = Kinv^T skew(t/|t|) R Kinv ----------------
  if (tid == 0) {
    double s0, c0, s1, c1, s2, c2;
    sincos(a0, &s0, &c0); sincos(a1, &s1, &c1); sincos(a2v, &s2, &c2);
    double Rz[9] = {c2, -s2, 0, s2, c2, 0, 0, 0, 1};
    double Ry[9] = {c1, 0, s1, 0, 1, 0, -s1, 0, c1};
    double Rx[9] = {1, 0, 0, 0, c0, -s0, 0, s0, c0};
    double YX[9], R[9];
    mm3d(Ry, Rx, YX); mm3d(Rz, YX, R);
    double tn = sqrt(t0 * t0 + t1 * t1 + t2 * t2);
    double n0 = t0 / tn, n1 = t1 / tn, n2 = t2 / tn;
    double Tn[9] = {0, -n2, n1, n2, 0, -n0, -n1, n0, 0};
    double Ee[9];
    mm3d(Tn, R, Ee);
    double ki[9];
    kinv3d(Kg, ki);
    double KT[9] = {ki[0], ki[3], ki[6], ki[1], ki[4], ki[7], ki[2], ki[5], ki[8]};
    double tmp[9], F[9];
    mm3d(KT, Ee, tmp); mm3d(tmp, ki, F);
#pragma unroll
    for (int q = 0; q < 9; ++q) out[q] = (float)F[q];
    out[9] = (float)a0; out[10] = (float)a1; out[11] = (float)a2v;
    out[12] = (float)t0; out[13] = (float)t1; out[14] = (float)t2;
  }
}

__global__ __launch_bounds__(256) void k_loss(const float* __restrict__ P1, const float* __restrict__ P2f,
                                              const float* __restrict__ out, double* __restrict__ lossAcc, int N) {
  const float f0 = out[0], f1 = out[1], f2 = out[2];
  const float f3 = out[3], f4 = out[4], f5 = out[5];
  const float f6 = out[6], f7 = out[7], f8 = out[8];
  double la = 0.0;
  for (int i = blockIdx.x * blockDim.x + threadIdx.x; i < N; i += gridDim.x * blockDim.x) {
    float x1 = P1[i], y1 = P1[N + i], x2 = P2f[i], y2 = P2f[N + i];
    float s = x2 * (f0 * x1 + f1 * y1 + f2) + y2 * (f3 * x1 + f4 * y1 + f5) + (f6 * x1 + f7 * y1 + f8);
    la += (double)fabsf(s);
  }
#pragma unroll
  for (int off = 32; off; off >>= 1) la += __shfl_down(la, off);
  __shared__ double wsum[4];
  int lane = threadIdx.x & 63, w = threadIdx.x >> 6;
  if (lane == 0) wsum[w] = la;
  __syncthreads();
  if (threadIdx.x == 0) {
    double s2 = wsum[0] + wsum[1] + wsum[2] + wsum[3];
    unsafeAtomicAdd(&lossAcc[blockIdx.x & 7], s2);
  }
}

__global__ __launch_bounds__(64) void k_fin(const double* __restrict__ acc, float* __restrict__ out, int N) {
  if (threadIdx.x == 0) {
    double a = 0.0;
#pragma unroll
    for (int c = 0; c < 8; ++c) a += acc[c];
    out[15] = (float)(a / (double)N);
  }
}

extern "C" void kernel_launch(void* const* d_in, const int* in_sizes, int n_in,
                              void* d_out, int out_size, void* d_ws, size_t ws_size,
                              hipStream_t stream) {
  const float* P1 = (const float*)d_in[0];
  const float* P2f = (const float*)d_in[1];
  const float* K = (const float*)d_in[2];
  float* out = (float*)d_out;
  double* ws = (double*)d_ws;
  int N = in_sizes[0] / 3;

  hipLaunchKernelGGL(k_zero, dim3(1), dim3(256), 0, stream, ws);
  hipLaunchKernelGGL(k_mom, dim3(512), dim3(256), 0, stream, P1, P2f, K, ws, N);
  hipLaunchKernelGGL(k_iter, dim3(1), dim3(64), 0, stream, ws, K, out, N);
  hipLaunchKernelGGL(k_loss, dim3(512), dim3(256), 0, stream, P1, P2f, out, ws + 1800, N);
  hipLaunchKernelGGL(k_fin, dim3(1), dim3(64), 0, stream, ws + 1800, out, N);
}

// Round 4
// 198.410 us; speedup vs baseline: 1.1497x; 1.1497x over previous
//
#include <hip/hip_runtime.h>
#include <math.h>

// ---------------------------------------------------------------------------
// Epipolar GN solver via 4th-order moment sufficient statistics.
// Round-3 (resubmit): k_iter restructured for latency — shuffle-based 6x6 GJ
// inverse (augmented with v so lanes 36..41 end up holding upd), closed-form
// rotation chain, merged stages (5 barriers/iter), poly sincos, NR reciprocal
// (builtin v_rcp_f64), per-lane preloaded tables. k_fin folded into k_loss.
// ---------------------------------------------------------------------------

#define LAPL 0.01
#define LRR  0.1
static constexpr int TS  = 128;
static constexpr int TSP = 129;

__host__ __device__ constexpr int IDXe(int a, int b) { return (a + b) * (a + b + 1) / 2 + b; }

__device__ static const int EA6[6] = {0, 1, 0, 2, 1, 0};
__device__ static const int EB6[6] = {0, 0, 1, 0, 1, 2};
__device__ static const signed char QKt[21] = {0,0,0,0,0,0, 1,1,1,1,1, 2,2,2,2, 3,3,3, 4,4, 5};
__device__ static const signed char QLt[21] = {0,1,2,3,4,5, 1,2,3,4,5, 2,3,4,5, 3,4,5, 4,5, 5};

__device__ __forceinline__ double shfl64(double x, int lane) {
  int lo = __shfl(__double2loint(x), lane, 64);
  int hi = __shfl(__double2hiint(x), lane, 64);
  return __hiloint2double(hi, lo);
}
__device__ __forceinline__ double shflx64(double x, int mask) {
  int lo = __shfl_xor(__double2loint(x), mask, 64);
  int hi = __shfl_xor(__double2hiint(x), mask, 64);
  return __hiloint2double(hi, lo);
}
__device__ __forceinline__ double fastrcp(double x) {
  double r = __builtin_amdgcn_rcp(x);          // v_rcp_f64
  double e = fma(-x, r, 1.0); r = fma(r, e, r);
  e = fma(-x, r, 1.0); r = fma(r, e, r);
  return r;
}
// Taylor sincos, |x| < ~0.8, abs err < 3e-14 (angles here are < 0.2)
__device__ __forceinline__ void sc_poly(double x, double* s, double* c) {
  double x2 = x * x;
  double ss = 1.6059043836821613e-10;          // 1/13!
  ss = fma(ss, x2, -2.5052108385441720e-08);   // -1/11!
  ss = fma(ss, x2, 2.7557319223985893e-06);    // 1/9!
  ss = fma(ss, x2, -1.9841269841269841e-04);   // -1/7!
  ss = fma(ss, x2, 8.3333333333333333e-03);    // 1/5!
  ss = fma(ss, x2, -1.6666666666666666e-01);   // -1/3!
  *s = fma(ss * x2, x, x);
  double cc = -1.1470745597729725e-11;         // -1/14!
  cc = fma(cc, x2, 2.0876756987868099e-09);    // 1/12!
  cc = fma(cc, x2, -2.7557319223985888e-07);   // -1/10!
  cc = fma(cc, x2, 2.4801587301587302e-05);    // 1/8!
  cc = fma(cc, x2, -1.3888888888888889e-03);   // -1/6!
  cc = fma(cc, x2, 4.1666666666666666e-02);    // 1/4!
  cc = fma(cc, x2, -0.5);
  *c = fma(cc, x2, 1.0);
}

__device__ __forceinline__ void kinv3d(const float* K, double ki[9]) {
  double a = K[0], b = K[1], c = K[2], d = K[3], e = K[4], f = K[5], g = K[6], h = K[7], i = K[8];
  double A = (e * i - f * h), B = -(d * i - f * g), C = (d * h - e * g);
  double det = a * A + b * B + c * C;
  double r = 1.0 / det;
  ki[0] = A * r;  ki[1] = -(b * i - c * h) * r;  ki[2] =  (b * f - c * e) * r;
  ki[3] = B * r;  ki[4] =  (a * i - c * g) * r;  ki[5] = -(a * f - c * d) * r;
  ki[6] = C * r;  ki[7] = -(a * h - b * g) * r;  ki[8] =  (a * e - b * d) * r;
}
__device__ __forceinline__ void mm3d(const double* A, const double* B, double* C) {
#pragma unroll
  for (int i = 0; i < 3; ++i)
#pragma unroll
    for (int j = 0; j < 3; ++j)
      C[i * 3 + j] = A[i * 3 + 0] * B[0 * 3 + j] + A[i * 3 + 1] * B[1 * 3 + j] + A[i * 3 + 2] * B[2 * 3 + j];
}

// ws (doubles): [0..1800) 8x225 Mom partials; [1800..1808) loss slots; [1808] ticket
__global__ __launch_bounds__(256) void k_zero(double* ws) {
  for (int i = threadIdx.x; i < 1812; i += 256) ws[i] = 0.0;
}

__global__ __launch_bounds__(256) void k_mom(const float* __restrict__ P1, const float* __restrict__ P2f,
                                             const float* __restrict__ K, double* __restrict__ mom, int N) {
  __shared__ double md[2][15][TSP];
  double ki[9];
  kinv3d(K, ki);
  const int t = threadIdx.x;
  const int j2 = t / 15, j1 = t % 15;
  double ac0 = 0.0, ac1 = 0.0, ac2 = 0.0, ac3 = 0.0;
  for (int base = blockIdx.x * TS; base < N; base += gridDim.x * TS) {
    {
      const int f = t >> 7;
      const int p = t & 127;
      const int idx = base + p;
      double m[15];
      if (idx < N) {
        const float* P = f ? P2f : P1;
        double x = (double)P[idx], y = (double)P[N + idx];
        double u = ki[0] * x + ki[1] * y + ki[2];
        double v = ki[3] * x + ki[4] * y + ki[5];
        double pu[5], pv[5];
        pu[0] = 1.0; pv[0] = 1.0;
        pu[1] = u;  pv[1] = v;
        pu[2] = pu[1] * pu[1]; pv[2] = pv[1] * pv[1];
        pu[3] = pu[2] * pu[1]; pv[3] = pv[2] * pv[1];
        pu[4] = pu[2] * pu[2]; pv[4] = pv[2] * pv[2];
#pragma unroll
        for (int d = 0; d <= 4; ++d)
#pragma unroll
          for (int bb = 0; bb <= d; ++bb)
            m[(d * (d + 1)) / 2 + bb] = pu[d - bb] * pv[bb];
      } else {
#pragma unroll
        for (int q = 0; q < 15; ++q) m[q] = 0.0;
      }
#pragma unroll
      for (int q = 0; q < 15; ++q) md[f][q][p] = m[q];
    }
    __syncthreads();
    if (t < 225) {
      for (int p = 0; p < TS; p += 4) {
        ac0 = fma(md[1][j2][p + 0], md[0][j1][p + 0], ac0);
        ac1 = fma(md[1][j2][p + 1], md[0][j1][p + 1], ac1);
        ac2 = fma(md[1][j2][p + 2], md[0][j1][p + 2], ac2);
        ac3 = fma(md[1][j2][p + 3], md[0][j1][p + 3], ac3);
      }
    }
    __syncthreads();
  }
  if (t < 225) unsafeAtomicAdd(&mom[(blockIdx.x & 7) * 225 + t], (ac0 + ac1) + (ac2 + ac3));
}

__global__ __launch_bounds__(64) void k_iter(const double* __restrict__ mom, const float* __restrict__ Kg,
                                             float* __restrict__ out, int N) {
  __shared__ struct {
    double Mom[225];
    double G[36 * 37];
    double U0[81];
    double zd[7][9];
    double gg[36];
    double w0[9];
    double uu[36];
    double Ps[6];
    double P2s;
    double Y[63];
    double Qs[36];
    double Cs[6];
    int mul9[81];
    int gcnt[36];
    int gpr[36 * 4];
  } S;
  const int tid = threadIdx.x;
  const double dN = (double)N;
  const double invN = 1.0 / dN;
  const double inv2 = invN * invN;

  // ---------------- prologue: tables ----------------
  for (int i = tid; i < 225; i += 64) {
    double a = 0.0;
#pragma unroll
    for (int c = 0; c < 8; ++c) a += mom[c * 225 + i];
    S.Mom[i] = a;
  }
  for (int i = tid; i < 81; i += 64) {
    int A = i / 9, B = i % 9, ia = A / 3, ja = A % 3, ib = B / 3, jb = B % 3;
    int a2 = (ia == 0) + (ib == 0), b2 = (ia == 1) + (ib == 1);
    int a1 = (ja == 0) + (jb == 0), b1 = (ja == 1) + (jb == 1);
    S.mul9[i] = IDXe(a2, b2) * 6 + IDXe(a1, b1);
  }
  __syncthreads();
  for (int i = tid; i < 1296; i += 64) {
    int ga = i / 36, de = i % 36;
    int g2 = ga / 6, g1 = ga % 6, d2 = de / 6, d1 = de % 6;
    int a2 = EA6[g2] + EA6[d2], b2 = EB6[g2] + EB6[d2];
    int a1 = EA6[g1] + EA6[d1], b1 = EB6[g1] + EB6[d1];
    S.G[ga * 37 + de] = S.Mom[IDXe(a2, b2) * 15 + IDXe(a1, b1)];
  }
  for (int i = tid; i < 81; i += 64) {
    int ga = S.mul9[i];
    S.U0[i] = S.Mom[(ga / 6) * 15 + (ga % 6)];
  }
  if (tid == 0) {
    for (int d = 0; d < 36; ++d) S.gcnt[d] = 0;
    for (int AB = 0; AB < 81; ++AB) {
      int d = S.mul9[AB];
      S.gpr[d * 4 + S.gcnt[d]] = AB;   // multiplicity provably <= 4 (2x2)
      S.gcnt[d]++;
    }
  }
  __syncthreads();

  // ---------------- per-lane register preloads ----------------
  double Grow[36];
  {
    int gr = (tid < 36) ? tid : 0;
#pragma unroll
    for (int q = 0; q < 36; ++q) Grow[q] = S.G[gr * 37 + q];
  }
  const int yA = (tid < 63) ? (tid % 9) : 0;
  const int yl = (tid < 63) ? (tid / 9) : 0;
  int m9r[9];
#pragma unroll
  for (int B = 0; B < 9; ++B) m9r[B] = S.mul9[yA * 9 + B];
  double u0r[9];
  {
    int wA = (tid >= 36 && tid < 45) ? (tid - 36) : 0;
#pragma unroll
    for (int B = 0; B < 9; ++B) u0r[B] = S.U0[wA * 9 + B];
  }
  int gA[4], gB[4];
  double gw[4];
  {
    int d = (tid < 36) ? tid : 0;
    int n = S.gcnt[d];
#pragma unroll
    for (int q = 0; q < 4; ++q) {
      int pr = (q < n) ? S.gpr[d * 4 + q] : 0;
      gA[q] = pr / 9; gB[q] = pr % 9;
      gw[q] = (q < n) ? 1.0 : 0.0;
    }
  }
  int qk = 0, ql = 0;
  if (tid < 21) { qk = QKt[tid]; ql = QLt[tid]; }
  int r6, c6;
  if (tid < 36)      { r6 = tid / 6;  c6 = tid % 6; }
  else if (tid < 42) { r6 = tid - 36; c6 = 6; }
  else               { r6 = 0;        c6 = 0; }

  // ---------------- GN iterations (fp64) ----------------
  double a0 = 0.0, a1 = 0.0, a2v = 0.0;
  double t0 = 0.0, t1 = 0.0, t2 = -0.95;
  double min_loss = 1e10;

#pragma unroll 1
  for (int it = 0; it < 100; ++it) {
    // S0: sincos on lanes 0..2, shfl broadcast
    double myang = (tid == 0) ? a0 : (tid == 1) ? a1 : a2v;
    double ss_, cc_;
    sc_poly(myang, &ss_, &cc_);
    const double cx = shfl64(cc_, 0), cy = shfl64(cc_, 1), cz = shfl64(cc_, 2);
    const double sx = shfl64(ss_, 0), sy = shfl64(ss_, 1), sz = shfl64(ss_, 2);

    // S1+S2: closed-form chain + publish (lane 0)
    if (tid == 0) {
      double czcy = cz * cy, czsy = cz * sy, szcy = sz * cy, szsy = sz * sy;
      double R0 = czcy;
      double R1 = czsy * sx - sz * cx;
      double R2 = czsy * cx + sz * sx;
      double R3 = szcy;
      double R4 = szsy * sx + cz * cx;
      double R5 = szsy * cx - cz * sx;
      double R6 = -sy;
      double R7 = cy * sx;
      double R8 = cy * cx;
      double y0 = -czsy, y1 = czcy * sx, y2 = czcy * cx;
      double y3 = -szsy, y4 = szcy * sx, y5 = szcy * cx;
      double y6 = -cy,   y7 = -(sy * sx), y8 = -(sy * cx);
      // E = Tm*R
      S.zd[0][0] = t1 * R6 - t2 * R3;  S.zd[0][1] = t1 * R7 - t2 * R4;  S.zd[0][2] = t1 * R8 - t2 * R5;
      S.zd[0][3] = t2 * R0 - t0 * R6;  S.zd[0][4] = t2 * R1 - t0 * R7;  S.zd[0][5] = t2 * R2 - t0 * R8;
      S.zd[0][6] = t0 * R3 - t1 * R0;  S.zd[0][7] = t0 * R4 - t1 * R1;  S.zd[0][8] = t0 * R5 - t1 * R2;
      // M0 = Tm*rxd, rxd = [0,R2,-R1 | 0,R5,-R4 | 0,R8,-R7]
      S.zd[1][0] = 0.0;  S.zd[1][1] = t1 * R8 - t2 * R5;  S.zd[1][2] = t2 * R4 - t1 * R7;
      S.zd[1][3] = 0.0;  S.zd[1][4] = t2 * R2 - t0 * R8;  S.zd[1][5] = t0 * R7 - t2 * R1;
      S.zd[1][6] = 0.0;  S.zd[1][7] = t0 * R5 - t1 * R2;  S.zd[1][8] = t1 * R1 - t0 * R4;
      // M1 = Tm*ryd
      S.zd[2][0] = t1 * y6 - t2 * y3;  S.zd[2][1] = t1 * y7 - t2 * y4;  S.zd[2][2] = t1 * y8 - t2 * y5;
      S.zd[2][3] = t2 * y0 - t0 * y6;  S.zd[2][4] = t2 * y1 - t0 * y7;  S.zd[2][5] = t2 * y2 - t0 * y8;
      S.zd[2][6] = t0 * y3 - t1 * y0;  S.zd[2][7] = t0 * y4 - t1 * y1;  S.zd[2][8] = t0 * y5 - t1 * y2;
      // M2 = Tm*rzd, rzd = [-R3,-R4,-R5 | R0,R1,R2 | 0,0,0]
      S.zd[3][0] = -t2 * R0;  S.zd[3][1] = -t2 * R1;  S.zd[3][2] = -t2 * R2;
      S.zd[3][3] = -t2 * R3;  S.zd[3][4] = -t2 * R4;  S.zd[3][5] = -t2 * R5;
      S.zd[3][6] = t1 * R3 + t0 * R0;  S.zd[3][7] = t1 * R4 + t0 * R1;  S.zd[3][8] = t1 * R5 + t0 * R2;
      // M3, M4, M5 (DTk * R)
      S.zd[4][0] = 0.0; S.zd[4][1] = 0.0; S.zd[4][2] = 0.0;
      S.zd[4][3] = -R6; S.zd[4][4] = -R7; S.zd[4][5] = -R8;
      S.zd[4][6] = R3;  S.zd[4][7] = R4;  S.zd[4][8] = R5;
      S.zd[5][0] = R6;  S.zd[5][1] = R7;  S.zd[5][2] = R8;
      S.zd[5][3] = 0.0; S.zd[5][4] = 0.0; S.zd[5][5] = 0.0;
      S.zd[5][6] = -R0; S.zd[5][7] = -R1; S.zd[5][8] = -R2;
      S.zd[6][0] = -R3; S.zd[6][1] = -R4; S.zd[6][2] = -R5;
      S.zd[6][3] = R0;  S.zd[6][4] = R1;  S.zd[6][5] = R2;
      S.zd[6][6] = 0.0; S.zd[6][7] = 0.0; S.zd[6][8] = 0.0;
    }
    __syncthreads();

    // S3: g (lanes<36) ; w0 = U0*e (lanes 36..44)
    if (tid < 36) {
      double acc = 0.0;
#pragma unroll
      for (int q = 0; q < 4; ++q)
        acc = fma(gw[q], S.zd[0][gA[q]] * S.zd[0][gB[q]], acc);
      S.gg[tid] = acc;
    } else if (tid < 45) {
      double acc = 0.0;
#pragma unroll
      for (int B = 0; B < 9; ++B) acc = fma(u0r[B], S.zd[0][B], acc);
      S.w0[tid - 36] = acc;
    }
    __syncthreads();

    // S4: u = G*g (lanes<36) ; Ps / P2s (lanes 36..42)
    if (tid < 36) {
      double acc = 0.0;
#pragma unroll
      for (int q = 0; q < 36; ++q) acc = fma(Grow[q], S.gg[q], acc);
      S.uu[tid] = acc;
    } else if (tid < 43) {
      int k = tid - 36;
      int rp = (k < 6) ? (1 + k) : 0;
      double acc = 0.0;
#pragma unroll
      for (int A = 0; A < 9; ++A) acc = fma(S.zd[rp][A], S.w0[A], acc);
      if (k < 6) S.Ps[k] = acc; else S.P2s = acc;
    }
    __syncthreads();

    // S5: Y[l][A] = sum_B uu[mul9[A,B]] * zd[l][B]   (63 lanes)
    {
      double acc = 0.0;
#pragma unroll
      for (int B = 0; B < 9; ++B) acc = fma(S.uu[m9r[B]], S.zd[yl][B], acc);
      if (tid < 63) S.Y[tid] = acc;
    }
    __syncthreads();

    // S6: Q (21 lanes, symmetric) ; C (6 lanes)
    if (tid < 21) {
      double acc = 0.0;
#pragma unroll
      for (int A = 0; A < 9; ++A) acc = fma(S.zd[1 + qk][A], S.Y[(1 + ql) * 9 + A], acc);
      S.Qs[qk * 6 + ql] = acc;
      S.Qs[ql * 6 + qk] = acc;
    } else if (tid < 27) {
      int k = tid - 21;
      double acc = 0.0;
#pragma unroll
      for (int A = 0; A < 9; ++A) acc = fma(S.zd[1 + k][A], S.Y[A], acc);
      S.Cs[k] = acc;
    }
    __syncthreads();

    // S7: assemble M (lanes<36) and v (lanes 36..41), element-per-lane
    double tn = sqrt(t0 * t0 + t1 * t1 + t2 * t2);
    double rbf = tn - 1.0;
    double btc = 2.0 * LAPL * rbf * fastrcp(tn);
    double P2v = S.P2s;
    double curloss = P2v * invN + LAPL * rbf * rbf;
    double m = 0.0, mold = 0.0;
    if (tid < 36) {
      int k = r6, l = c6;
      double bk = (k == 3) ? btc * t0 : (k == 4) ? btc * t1 : (k == 5) ? btc * t2 : 0.0;
      double bl = (l == 3) ? btc * t0 : (l == 4) ? btc * t1 : (l == 5) ? btc * t2 : 0.0;
      m = 4.0 * inv2 * S.Qs[tid] + 2.0 * inv2 * (bk * S.Ps[l] + bl * S.Ps[k]) + bk * bl * invN;
      mold = m;
    } else if (tid < 42) {
      int k = r6;
      double bk = (k == 3) ? btc * t0 : (k == 4) ? btc * t1 : (k == 5) ? btc * t2 : 0.0;
      double dcf = LAPL * rbf * rbf * invN;
      m = 2.0 * inv2 * S.Cs[k] + (2.0 * dcf * invN) * S.Ps[k] + bk * inv2 * P2v + bk * dcf;
    }

    // In-place Gauss-Jordan inverse with augmented v column, all via shuffles.
    // Lane r*6+c holds M[r][c]; lane 36+r holds v[r] (becomes upd[r]).
#pragma unroll
    for (int p = 0; p < 6; ++p) {
      double piv = shfl64(m, p * 7);
      double d = fastrcp(piv);
      double prow = shfl64(m, (c6 == 6) ? (36 + p) : (p * 6 + c6));
      double f = shfl64(m, r6 * 6 + p);
      double nm = fma(-f, prow * d, m);
      if (c6 == p) nm = -f * d;
      if (r6 == p) nm = m * d;
      if (r6 == p && c6 == p) nm = d;
      m = nm;
    }

    // bad_inv: max|Minv*Mold - I|
    double merr = 0.0;
    if (tid < 36) {
      double s2 = (r6 == c6) ? -1.0 : 0.0;
#pragma unroll
      for (int k = 0; k < 6; ++k)
        s2 = fma(shfl64(m, r6 * 6 + k), shfl64(mold, k * 6 + c6), s2);
      merr = fabs(s2);
    }
#pragma unroll
    for (int off = 32; off; off >>= 1) merr = fmax(merr, shflx64(merr, off));

    bool stop_now = (merr > 0.1) || (curloss > min_loss);
    if (stop_now) break;   // latched stop == params frozen forever

    a0  -= LRR * shfl64(m, 36);
    a1  -= LRR * shfl64(m, 37);
    a2v -= LRR * shfl64(m, 38);
    t0  -= LRR * shfl64(m, 39);
    t1  -= LRR * shfl64(m, 40);
    t2  -= LRR * shfl64(m, 41);
    min_loss = curloss;
  }

  // ---------------- epilogue: F = Kinv^T skew(t/|t|) R Kinv ----------------
  if (tid == 0) {
    double s0, c0, s1, c1, s2, c2;
    sc_poly(a0, &s0, &c0); sc_poly(a1, &s1, &c1); sc_poly(a2v, &s2, &c2);
    double Rz[9] = {c2, -s2, 0, s2, c2, 0, 0, 0, 1};
    double Ry[9] = {c1, 0, s1, 0, 1, 0, -s1, 0, c1};
    double Rx[9] = {1, 0, 0, 0, c0, -s0, 0, s0, c0};
    double YX[9], R[9];
    mm3d(Ry, Rx, YX); mm3d(Rz, YX, R);
    double tn = sqrt(t0 * t0 + t1 * t1 + t2 * t2);
    double n0 = t0 / tn, n1 = t1 / tn, n2 = t2 / tn;
    double Tn[9] = {0, -n2, n1, n2, 0, -n0, -n1, n0, 0};
    double Ee[9];
    mm3d(Tn, R, Ee);
    double ki[9];
    kinv3d(Kg, ki);
    double KT[9] = {ki[0], ki[3], ki[6], ki[1], ki[4], ki[7], ki[2], ki[5], ki[8]};
    double tmp[9], F[9];
    mm3d(KT, Ee, tmp); mm3d(tmp, ki, F);
#pragma unroll
    for (int q = 0; q < 9; ++q) out[q] = (float)F[q];
    out[9] = (float)a0; out[10] = (float)a1; out[11] = (float)a2v;
    out[12] = (float)t0; out[13] = (float)t1; out[14] = (float)t2;
  }
}

__global__ __launch_bounds__(256) void k_loss(const float* __restrict__ P1, const float* __restrict__ P2f,
                                              float* __restrict__ out, double* __restrict__ ws, int N) {
  double* lossAcc = ws + 1800;
  unsigned* ticket = (unsigned*)(ws + 1808);
  const float f0 = out[0], f1 = out[1], f2 = out[2];
  const float f3 = out[3], f4 = out[4], f5 = out[5];
  const float f6 = out[6], f7 = out[7], f8 = out[8];
  double la = 0.0;
  for (int i = blockIdx.x * blockDim.x + threadIdx.x; i < N; i += gridDim.x * blockDim.x) {
    float x1 = P1[i], y1 = P1[N + i], x2 = P2f[i], y2 = P2f[N + i];
    float s = x2 * (f0 * x1 + f1 * y1 + f2) + y2 * (f3 * x1 + f4 * y1 + f5) + (f6 * x1 + f7 * y1 + f8);
    la += (double)fabsf(s);
  }
#pragma unroll
  for (int off = 32; off; off >>= 1) la += __shfl_down(la, off);
  __shared__ double wsum[4];
  int lane = threadIdx.x & 63, w = threadIdx.x >> 6;
  if (lane == 0) wsum[w] = la;
  __syncthreads();
  if (threadIdx.x == 0) {
    double s2 = wsum[0] + wsum[1] + wsum[2] + wsum[3];
    unsafeAtomicAdd(&lossAcc[blockIdx.x & 7], s2);
    __threadfence();
    unsigned old = atomicAdd(ticket, 1u);
    if (old == gridDim.x - 1) {   // last block: finalize loss
      __threadfence();
      double tot = 0.0;
#pragma unroll
      for (int c = 0; c < 8; ++c) tot += unsafeAtomicAdd(&lossAcc[c], 0.0);
      out[15] = (float)(tot / (double)N);
    }
  }
}

extern "C" void kernel_launch(void* const* d_in, const int* in_sizes, int n_in,
                              void* d_out, int out_size, void* d_ws, size_t ws_size,
                              hipStream_t stream) {
  const float* P1 = (const float*)d_in[0];
  const float* P2f = (const float*)d_in[1];
  const float* K = (const float*)d_in[2];
  float* out = (float*)d_out;
  double* ws = (double*)d_ws;
  int N = in_sizes[0] / 3;

  hipLaunchKernelGGL(k_zero, dim3(1), dim3(256), 0, stream, ws);
  hipLaunchKernelGGL(k_mom, dim3(512), dim3(256), 0, stream, P1, P2f, K, ws, N);
  hipLaunchKernelGGL(k_iter, dim3(1), dim3(64), 0, stream, ws, K, out, N);
  hipLaunchKernelGGL(k_loss, dim3(512), dim3(256), 0, stream, P1, P2f, out, ws, N);
}